// Round 14
// baseline (759.437 us; speedup 1.0000x reference)
//
#include <hip/hip_runtime.h>
#include <hip/hip_bf16.h>
#include <hip/hip_fp16.h>

#define NN 200000
#define NE 800000
#define HID 256
#define SCAN_NBLK 196     // 196 * 1024 = 200704 >= NN+1

typedef __attribute__((ext_vector_type(8))) _Float16 f16x8;
typedef __attribute__((ext_vector_type(4))) float    f32x4;

// ---------- direct global->LDS DMA (16B/lane; LDS dest = wave base + lane*16) ----------
__device__ __forceinline__ void gload16(const void* g, void* l) {
    __builtin_amdgcn_global_load_lds(
        (__attribute__((address_space(1))) void*)(g),
        (__attribute__((address_space(3))) void*)(l), 16, 0, 0);
}

// ---------- packed f16 helpers ----------
__device__ __forceinline__ float2 upk(unsigned int u) {
    __half2 h = __builtin_bit_cast(__half2, u);
    return make_float2(__low2float(h), __high2float(h));
}
__device__ __forceinline__ unsigned int pk(float a, float b) {
    __half2 h = __floats2half2_rn(a, b);
    return __builtin_bit_cast(unsigned int, h);
}

// ---------- input dtype helpers (runtime-dispatched via flags) ----------
__device__ __forceinline__ float bfu(unsigned short u) {
    return __uint_as_float(((unsigned int)u) << 16);
}
__device__ __forceinline__ unsigned short f2bf(float f) {
    unsigned int u = __float_as_uint(f);
    return (unsigned short)((u + 0x7FFFu + ((u >> 16) & 1u)) >> 16);
}
__device__ __forceinline__ float ldF(const void* p, size_t i, int bf) {
    return bf ? bfu(((const unsigned short*)p)[i]) : ((const float*)p)[i];
}
__device__ __forceinline__ float4 ld4(const void* p, size_t i, int bf) {
    if (bf) {
        ushort4 u = *reinterpret_cast<const ushort4*>((const unsigned short*)p + i);
        return make_float4(bfu(u.x), bfu(u.y), bfu(u.z), bfu(u.w));
    }
    return *reinterpret_cast<const float4*>((const float*)p + i);
}
__device__ __forceinline__ void ld8(const void* p, size_t i, int bf, float* v) {
    if (bf) {
        ushort4 u0 = *reinterpret_cast<const ushort4*>((const unsigned short*)p + i);
        ushort4 u1 = *reinterpret_cast<const ushort4*>((const unsigned short*)p + i + 4);
        v[0] = bfu(u0.x); v[1] = bfu(u0.y); v[2] = bfu(u0.z); v[3] = bfu(u0.w);
        v[4] = bfu(u1.x); v[5] = bfu(u1.y); v[6] = bfu(u1.z); v[7] = bfu(u1.w);
    } else {
        float4 a = *reinterpret_cast<const float4*>((const float*)p + i);
        float4 b = *reinterpret_cast<const float4*>((const float*)p + i + 4);
        v[0] = a.x; v[1] = a.y; v[2] = a.z; v[3] = a.w;
        v[4] = b.x; v[5] = b.y; v[6] = b.z; v[7] = b.w;
    }
}
__device__ __forceinline__ int ldE(const int* ei, size_t i, int i64) {
    return i64 ? ei[2 * i] : ei[i];
}

// ---------- detector: flags[0]=floats-are-bf16, flags[1]=edges-are-int64 ----------
__global__ void detect_kernel(const void* x, const int* ei, int* flags)
{
    if (threadIdx.x == 0 && blockIdx.x == 0) {
        const unsigned short* xu = (const unsigned short*)x;
        int good = 0;
        for (int k = 0; k < 128; ++k) {
            float a = fabsf(bfu(xu[2 * k]));
            if (a == 0.f || (a >= 9.3e-10f && a <= 64.f)) ++good;
        }
        flags[0] = (good >= 64) ? 1 : 0;
        int zeros = 0;
        for (int k = 0; k < 128; ++k)
            if (ei[2 * k + 1] == 0) ++zeros;
        flags[1] = (zeros >= 64) ? 1 : 0;
    }
}

// ---------- weight prep: WT[n][256] = f16(W[k][n]) ----------
__global__ __launch_bounds__(256) void prepT256_kernel(
    const void* __restrict__ W, const int* __restrict__ flags, __half* __restrict__ WT)
{
    const int bf = flags[0];
    int id = blockIdx.x * 256 + threadIdx.x;     // 65536 total
    int k = id & 255, n = id >> 8;
    WT[(size_t)n * 256 + k] = __float2half_rn(ldF(W, (size_t)k * 256 + n, bf));
}

// ---------- weight prep: WT[n][512]: k<256 -> Rw[k][n], k>=256 -> Sw[k-256][n] ----------
__global__ __launch_bounds__(256) void prepT512_kernel(
    const void* __restrict__ Rw, const void* __restrict__ Sw,
    const int* __restrict__ flags, __half* __restrict__ WT)
{
    const int bf = flags[0];
    int id = blockIdx.x * 256 + threadIdx.x;     // 131072 total
    int k = id & 511, n = id >> 9;
    const void* src = (k < 256) ? Rw : Sw;
    WT[(size_t)n * 512 + k] = __float2half_rn(ldF(src, (size_t)(k & 255) * 256 + n, bf));
}

// ---------- weight prep: W8T[16][256]: c<4 -> rw3[k][c], c<8 -> sw3[k][c-4], else 0 ----------
__global__ __launch_bounds__(256) void prepW8_kernel(
    const void* __restrict__ rw3, const void* __restrict__ sw3,
    const int* __restrict__ flags, __half* __restrict__ W8T)
{
    const int bf = flags[0];
    int id = blockIdx.x * 256 + threadIdx.x;     // 4096 total
    int c = id >> 8, k = id & 255;
    float v = 0.f;
    if (c < 4)      v = ldF(rw3, (size_t)k * 4 + c, bf);
    else if (c < 8) v = ldF(sw3, (size_t)k * 4 + (c - 4), bf);
    W8T[(size_t)c * 256 + k] = __float2half_rn(v);
}

// ---------- frontT: T = relu(xs@e1+be1) (f16), reg-resident weights ----------
__global__ __launch_bounds__(256) void frontT_kernel(
    const void* __restrict__ x,
    const void* __restrict__ e1, const void* __restrict__ be1,
    const int* __restrict__ flags, __half* __restrict__ T)
{
    const int bf = flags[0];
    const int t = threadIdx.x;
    const int wave = t >> 6, lane = t & 63;
    const int half = lane >> 5, l32 = lane & 31;
    const int j0 = l32 * 8;

    float ev[6][8], be[8];
    ld8(be1, j0, bf, be);
#pragma unroll
    for (int k = 0; k < 6; ++k) ld8(e1, (size_t)k * HID + j0, bf, ev[k]);

    const int slot = blockIdx.x * 4 + wave;
    const int nslots = gridDim.x * 4;
    for (int n = slot * 2 + half; n < NN; n += nslots * 2) {
        float xs[6];
#pragma unroll
        for (int k = 0; k < 6; ++k) xs[k] = ldF(x, (size_t)n * 10 + 4 + k, bf);
        float a[8];
#pragma unroll
        for (int jj = 0; jj < 8; ++jj) a[jj] = be[jj];
#pragma unroll
        for (int k = 0; k < 6; ++k)
#pragma unroll
            for (int jj = 0; jj < 8; ++jj)
                a[jj] = fmaf(xs[k], ev[k][jj], a[jj]);
        uint4 o;
        o.x = pk(fmaxf(a[0], 0.f), fmaxf(a[1], 0.f));
        o.y = pk(fmaxf(a[2], 0.f), fmaxf(a[3], 0.f));
        o.z = pk(fmaxf(a[4], 0.f), fmaxf(a[5], 0.f));
        o.w = pk(fmaxf(a[6], 0.f), fmaxf(a[7], 0.f));
        *reinterpret_cast<uint4*>(&T[(size_t)n * HID + j0]) = o;
    }
}

// ---------- frontW: weak = relu(xs@w1+b1)@w2 + b2 (f32), reg-resident weights ----------
__global__ __launch_bounds__(256) void frontW_kernel(
    const void* __restrict__ x,
    const void* __restrict__ w1, const void* __restrict__ b1,
    const void* __restrict__ w2, const void* __restrict__ b2,
    const int* __restrict__ flags, float* __restrict__ weakO)
{
    const int bf = flags[0];
    const int t = threadIdx.x;
    const int wave = t >> 6, lane = t & 63;
    const int half = lane >> 5, l32 = lane & 31;
    const int j0 = l32 * 8;

    float wv[6][8], bb[8], w2r[8][4];
    ld8(b1, j0, bf, bb);
#pragma unroll
    for (int k = 0; k < 6; ++k) ld8(w1, (size_t)k * HID + j0, bf, wv[k]);
#pragma unroll
    for (int jj = 0; jj < 8; ++jj) {
        float4 r = ld4(w2, (size_t)(j0 + jj) * 4, bf);
        w2r[jj][0] = r.x; w2r[jj][1] = r.y; w2r[jj][2] = r.z; w2r[jj][3] = r.w;
    }
    float b2v[4];
#pragma unroll
    for (int c = 0; c < 4; ++c) b2v[c] = ldF(b2, c, bf);

    const int slot = blockIdx.x * 4 + wave;
    const int nslots = gridDim.x * 4;
    for (int n = slot * 2 + half; n < NN; n += nslots * 2) {
        float xs[6];
#pragma unroll
        for (int k = 0; k < 6; ++k) xs[k] = ldF(x, (size_t)n * 10 + 4 + k, bf);
        float a[8];
#pragma unroll
        for (int jj = 0; jj < 8; ++jj) a[jj] = bb[jj];
#pragma unroll
        for (int k = 0; k < 6; ++k)
#pragma unroll
            for (int jj = 0; jj < 8; ++jj)
                a[jj] = fmaf(xs[k], wv[k][jj], a[jj]);
        float wa[4] = {0.f, 0.f, 0.f, 0.f};
#pragma unroll
        for (int jj = 0; jj < 8; ++jj) {
            float av = fmaxf(a[jj], 0.f);
#pragma unroll
            for (int c = 0; c < 4; ++c) wa[c] = fmaf(av, w2r[jj][c], wa[c]);
        }
#pragma unroll
        for (int off = 16; off >= 1; off >>= 1)
#pragma unroll
            for (int c = 0; c < 4; ++c) wa[c] += __shfl_xor(wa[c], off);
        if (l32 == 0) {
            float4 w = {wa[0] + b2v[0], wa[1] + b2v[1], wa[2] + b2v[2], wa[3] + b2v[3]};
            *reinterpret_cast<float4*>(&weakO[(size_t)n * 4]) = w;
        }
    }
}

// ---------- MFMA GEMM: OUT = (relu?)(Acat @ Wcat + bias) ----------
// Block tile: 256 rows x 256 cols, 1024 threads = 16 waves in 4x4 grid,
// each wave 64x64. 2 DMAs/thread per K-step; 2 blocks/CU = 32 waves (full).
// In-place safe: block reads only its own 256 rows, writes after K-loop.
// Staging via global_load_lds, pre-swizzled global chunk: c=(t&3)^((t>>3)&3).
template<int KTOT, int RELU>
__global__ __launch_bounds__(1024) void mfma_gemm_kernel(
    const __half* A0, const __half* __restrict__ A1,
    const __half* __restrict__ WT, const void* __restrict__ bias,
    const int* __restrict__ flags, __half* OUT)
{
    const int bf = flags[0];
    __shared__ alignas(16) __half As[256 * 32];
    __shared__ alignas(16) __half Ws[256 * 32];

    const int t    = threadIdx.x;
    const int bm   = blockIdx.x * 256;
    const int lane = t & 63;
    const int w    = t >> 6;                 // 16 waves
    const int wr   = w >> 2, wc = w & 3;     // 4 x 4 wave grid
    const int lr   = lane & 15, lg = lane >> 4;

    // per-thread staging coords (constant across K-steps): row = t>>2
    const int srow = t >> 2;
    int agm = bm + srow; if (agm > NN - 1) agm = NN - 1;   // clamp: pad rows discarded
    const int sc_g = (t & 3) ^ ((t >> 3) & 3);             // pre-swizzled global chunk

    f32x4 acc[4][4] = {};

    for (int k0 = 0; k0 < KTOT; k0 += 32) {
        __syncthreads();
        // A tile: 256 rows x 32 k, one 16B DMA per thread
        {
            const __half* src = (KTOT == 512 && k0 >= 256) ? A1 : A0;
            const int kk0 = k0 & 255;
            gload16(&src[(size_t)agm * HID + kk0 + sc_g * 8], &As[w * 512]);
        }
        // W tile: 256 n x 32 k, one 16B DMA per thread
        gload16(&WT[(size_t)srow * KTOT + k0 + sc_g * 8], &Ws[w * 512]);
        __syncthreads();

        f16x8 a[4], b[4];
#pragma unroll
        for (int i = 0; i < 4; ++i) {
            int row = wr * 64 + i * 16 + lr;
            int sc = lg ^ ((row >> 1) & 3);
            a[i] = *reinterpret_cast<const f16x8*>(&As[row * 32 + sc * 8]);
        }
#pragma unroll
        for (int j = 0; j < 4; ++j) {
            int n = wc * 64 + j * 16 + lr;
            int sc = lg ^ ((n >> 1) & 3);
            b[j] = *reinterpret_cast<const f16x8*>(&Ws[n * 32 + sc * 8]);
        }
#pragma unroll
        for (int i = 0; i < 4; ++i)
#pragma unroll
            for (int j = 0; j < 4; ++j)
                acc[i][j] = __builtin_amdgcn_mfma_f32_16x16x32_f16(a[i], b[j], acc[i][j], 0, 0, 0);
    }

    float bv[4];
#pragma unroll
    for (int j = 0; j < 4; ++j) bv[j] = ldF(bias, wc * 64 + j * 16 + lr, bf);
#pragma unroll
    for (int i = 0; i < 4; ++i) {
        int rowBase = bm + wr * 64 + i * 16 + lg * 4;
#pragma unroll
        for (int r = 0; r < 4; ++r) {
            int gr = rowBase + r;
            if (gr < NN) {
#pragma unroll
                for (int j = 0; j < 4; ++j) {
                    int col = wc * 64 + j * 16 + lr;
                    float v = acc[i][j][r] + bv[j];
                    if (RELU) v = fmaxf(v, 0.f);
                    OUT[(size_t)gr * HID + col] = __float2half_rn(v);
                }
            }
        }
    }
}

// ---------- CSR build ----------
__global__ __launch_bounds__(256) void zeroI_kernel(int* __restrict__ p, int n)
{
    int i = blockIdx.x * 256 + threadIdx.x;
    if (i < n) p[i] = 0;
}

__global__ __launch_bounds__(256) void count_kernel(
    const int* __restrict__ ei, const int* __restrict__ flags, int* __restrict__ rowptr)
{
    const int i64 = flags[1];
    int e = blockIdx.x * 256 + threadIdx.x;
    if (e >= NE) return;
    int tgt = ldE(ei, (size_t)NE + e, i64);
    if ((unsigned)tgt < NN) atomicAdd(&rowptr[tgt + 1], 1);
}

// ---------- multi-block inclusive scan over rowptr[0..NN] ----------
__global__ __launch_bounds__(256) void scanA_kernel(
    const int* __restrict__ rowptr, int* __restrict__ partials)
{
    __shared__ int red[256];
    const int b = blockIdx.x, t = threadIdx.x;
    int base = b * 1024 + t * 4;
    int s = 0;
#pragma unroll
    for (int k = 0; k < 4; ++k) {
        int i = base + k;
        if (i <= NN) s += rowptr[i];
    }
    red[t] = s;
    __syncthreads();
    for (int off = 128; off >= 1; off >>= 1) {
        if (t < off) red[t] += red[t + off];
        __syncthreads();
    }
    if (t == 0) partials[b] = red[0];
}

__global__ __launch_bounds__(256) void scanB_kernel(int* __restrict__ partials)
{
    __shared__ int ps[256];
    const int t = threadIdx.x;
    int v = (t < SCAN_NBLK) ? partials[t] : 0;
    ps[t] = v;
    __syncthreads();
    for (int off = 1; off < 256; off <<= 1) {
        int u = (t >= off) ? ps[t - off] : 0;
        __syncthreads();
        ps[t] += u;
        __syncthreads();
    }
    if (t < SCAN_NBLK) partials[t] = ps[t] - v;   // exclusive block offset
}

__global__ __launch_bounds__(256) void scanC_kernel(
    int* __restrict__ rowptr, const int* __restrict__ partials)
{
    __shared__ int ts[256];
    const int b = blockIdx.x, t = threadIdx.x;
    int base = b * 1024 + t * 4;
    int v[4];
    int s = 0;
#pragma unroll
    for (int k = 0; k < 4; ++k) {
        int i = base + k;
        v[k] = (i <= NN) ? rowptr[i] : 0;
        s += v[k];
    }
    ts[t] = s;
    __syncthreads();
    for (int off = 1; off < 256; off <<= 1) {
        int u = (t >= off) ? ts[t - off] : 0;
        __syncthreads();
        ts[t] += u;
        __syncthreads();
    }
    int run = ts[t] - s + partials[b];
#pragma unroll
    for (int k = 0; k < 4; ++k) {
        int i = base + k;
        run += v[k];
        if (i <= NN) rowptr[i] = run;
    }
}

__global__ __launch_bounds__(256) void fill_kernel(
    const int* __restrict__ ei, const int* __restrict__ flags,
    const int* __restrict__ rowptr, int* __restrict__ cursor, int* __restrict__ csr_src)
{
    const int i64 = flags[1];
    int e = blockIdx.x * 256 + threadIdx.x;
    if (e >= NE) return;
    int src = ldE(ei, (size_t)e, i64);
    int tgt = ldE(ei, (size_t)NE + e, i64);
    if ((unsigned)src >= NN || (unsigned)tgt >= NN) return;
    int pos = rowptr[tgt] + atomicAdd(&cursor[tgt], 1);
    csr_src[pos] = src;
}

// ---------- gather v2: AGG[n] = sum_{j in CSR(n)} H[src_j] ----------
// 2 rows per wave (32 lanes/row, uint4 = 16B/lane); 2-way edge unroll for MLP.
__global__ __launch_bounds__(256) void gather_kernel(
    const int* __restrict__ rowptr, const int* __restrict__ csr_src,
    const __half* __restrict__ H, __half* __restrict__ AGG)
{
    const int t = threadIdx.x;
    const int wave = t >> 6, lane = t & 63;
    const int half = lane >> 5, l32 = lane & 31;
    int n = blockIdx.x * 8 + wave * 2 + half;
    if (n >= NN) return;
    int beg = rowptr[n], end = rowptr[n + 1];
    float a[8] = {0.f, 0.f, 0.f, 0.f, 0.f, 0.f, 0.f, 0.f};
    const size_t col = (size_t)l32 * 8;
    int j = beg;
    for (; j + 2 <= end; j += 2) {
        int s0 = csr_src[j], s1 = csr_src[j + 1];
        uint4 q0 = *reinterpret_cast<const uint4*>(&H[(size_t)s0 * HID + col]);
        uint4 q1 = *reinterpret_cast<const uint4*>(&H[(size_t)s1 * HID + col]);
        float2 p;
        p = upk(q0.x); a[0] += p.x; a[1] += p.y;
        p = upk(q0.y); a[2] += p.x; a[3] += p.y;
        p = upk(q0.z); a[4] += p.x; a[5] += p.y;
        p = upk(q0.w); a[6] += p.x; a[7] += p.y;
        p = upk(q1.x); a[0] += p.x; a[1] += p.y;
        p = upk(q1.y); a[2] += p.x; a[3] += p.y;
        p = upk(q1.z); a[4] += p.x; a[5] += p.y;
        p = upk(q1.w); a[6] += p.x; a[7] += p.y;
    }
    if (j < end) {
        int s0 = csr_src[j];
        uint4 q0 = *reinterpret_cast<const uint4*>(&H[(size_t)s0 * HID + col]);
        float2 p;
        p = upk(q0.x); a[0] += p.x; a[1] += p.y;
        p = upk(q0.y); a[2] += p.x; a[3] += p.y;
        p = upk(q0.z); a[4] += p.x; a[5] += p.y;
        p = upk(q0.w); a[6] += p.x; a[7] += p.y;
    }
    uint4 o;
    o.x = pk(a[0], a[1]);
    o.y = pk(a[2], a[3]);
    o.z = pk(a[4], a[5]);
    o.w = pk(a[6], a[7]);
    *reinterpret_cast<uint4*>(&AGG[(size_t)n * HID + col]) = o;
}

// ---------- layer-3 skinny MFMA GEMM: [B3|C3] = h @ W8T^T ----------
__global__ __launch_bounds__(256) void gemv3_mfma_kernel(
    const __half* __restrict__ h, const __half* __restrict__ W8T,
    const void* __restrict__ rb3, const int* __restrict__ flags,
    float* __restrict__ B3, float* __restrict__ C3)
{
    const int bf = flags[0];
    __shared__ alignas(16) __half As[128 * 32];

    const int t    = threadIdx.x;
    const int bm   = blockIdx.x * 128;
    const int lane = t & 63;
    const int w    = t >> 6;                 // 4 waves, 32 rows each
    const int lr   = lane & 15, lg = lane >> 4;

    f32x4 acc[2] = {};

    for (int k0 = 0; k0 < HID; k0 += 32) {
        __syncthreads();
#pragma unroll
        for (int p = 0; p < 2; ++p) {
            int cid = p * 256 + t;
            int row = cid >> 2, c = cid & 3;
            int gm = bm + row;
            uint4 v = make_uint4(0, 0, 0, 0);
            if (gm < NN)
                v = *reinterpret_cast<const uint4*>(&h[(size_t)gm * HID + k0 + c * 8]);
            int sc = c ^ ((row >> 1) & 3);
            *reinterpret_cast<uint4*>(&As[row * 32 + sc * 8]) = v;
        }
        __syncthreads();

        f16x8 b = *reinterpret_cast<const f16x8*>(&W8T[(size_t)lr * HID + k0 + lg * 8]);
#pragma unroll
        for (int i = 0; i < 2; ++i) {
            int row = w * 32 + i * 16 + lr;
            int sc = lg ^ ((row >> 1) & 3);
            f16x8 a = *reinterpret_cast<const f16x8*>(&As[row * 32 + sc * 8]);
            acc[i] = __builtin_amdgcn_mfma_f32_16x16x32_f16(a, b, acc[i], 0, 0, 0);
        }
    }

    float rbv = (lr >= 4 && lr < 8) ? ldF(rb3, lr - 4, bf) : 0.f;
#pragma unroll
    for (int i = 0; i < 2; ++i) {
        int rowBase = bm + w * 32 + i * 16 + lg * 4;
#pragma unroll
        for (int r = 0; r < 4; ++r) {
            int gr = rowBase + r;
            if (gr < NN) {
                float v = acc[i][r];
                if (lr < 4)      B3[(size_t)gr * 4 + lr] = v;
                else if (lr < 8) C3[(size_t)gr * 4 + (lr - 4)] = v + rbv;
            }
        }
    }
}

// ---------- gather width-4: C3[n] += sum B3[src] ----------
__global__ __launch_bounds__(256) void gather3_kernel(
    const int* __restrict__ rowptr, const int* __restrict__ csr_src,
    const float* __restrict__ B3, float* __restrict__ C3)
{
    int n = blockIdx.x * 256 + threadIdx.x;
    if (n >= NN) return;
    int beg = rowptr[n], end = rowptr[n + 1];
    float4 acc = *reinterpret_cast<const float4*>(&C3[(size_t)n * 4]);
    for (int j = beg; j < end; ++j) {
        int s = csr_src[j];
        float4 v = *reinterpret_cast<const float4*>(&B3[(size_t)s * 4]);
        acc.x += v.x; acc.y += v.y; acc.z += v.z; acc.w += v.w;
    }
    *reinterpret_cast<float4*>(&C3[(size_t)n * 4]) = acc;
}

// ---------- final: confidence gating; dtype-dispatched output ----------
__global__ __launch_bounds__(256) void final_kernel(
    const float* __restrict__ weakO, const float* __restrict__ strongO,
    const int* __restrict__ flags, void* __restrict__ outv)
{
    const int bf = flags[0];
    int n = blockIdx.x * 256 + threadIdx.x;
    if (n >= NN) return;
    float4 w = *reinterpret_cast<const float4*>(&weakO[(size_t)n * 4]);
    float4 s = *reinterpret_cast<const float4*>(&strongO[(size_t)n * 4]);
    float mx = fmaxf(fmaxf(w.x, w.y), fmaxf(w.z, w.w));
    float e0 = expf(w.x - mx), e1 = expf(w.y - mx), e2 = expf(w.z - mx), e3 = expf(w.w - mx);
    float inv = 1.f / (e0 + e1 + e2 + e3);
    float p0 = e0 * inv, p1 = e1 * inv, p2 = e2 * inv, p3 = e3 * inv;
    const float m = 0.25f;
    float var = ((p0 - m) * (p0 - m) + (p1 - m) * (p1 - m) +
                 (p2 - m) * (p2 - m) + (p3 - m) * (p3 - m)) * 0.25f;
    float ent = -(p0 * logf(p0 + 1e-8f) + p1 * logf(p1 + 1e-8f) +
                  p2 * logf(p2 + 1e-8f) + p3 * logf(p3 + 1e-8f));
    ent *= 0.7213475204444817f;  // 1/log(4)
    float conf = 0.5f * (var + (1.f - ent));
    conf = fminf(fmaxf(conf, 0.f), 1.f);
    float o0 = conf * w.x + (1.f - conf) * s.x;
    float o1 = conf * w.y + (1.f - conf) * s.y;
    float o2 = conf * w.z + (1.f - conf) * s.z;
    float o3 = conf * w.w + (1.f - conf) * s.w;
    if (bf) {
        ushort4 u;
        u.x = f2bf(o0); u.y = f2bf(o1); u.z = f2bf(o2); u.w = f2bf(o3);
        *reinterpret_cast<ushort4*>((unsigned short*)outv + (size_t)n * 4) = u;
    } else {
        float4 o = {o0, o1, o2, o3};
        *reinterpret_cast<float4*>((float*)outv + (size_t)n * 4) = o;
    }
}

extern "C" void kernel_launch(void* const* d_in, const int* in_sizes, int n_in,
                              void* d_out, int out_size, void* d_ws, size_t ws_size,
                              hipStream_t stream)
{
    const void* x   = d_in[0];
    const int*  ei  = (const int*)d_in[1];
    const void* w1  = d_in[2];
    const void* b1  = d_in[3];
    const void* w2  = d_in[4];
    const void* b2  = d_in[5];
    const void* e1  = d_in[6];
    const void* be1 = d_in[7];
    const void* e2  = d_in[8];
    const void* be2 = d_in[9];
    const void* rw[4] = {d_in[10], d_in[13], d_in[16], d_in[19]};
    const void* rb[4] = {d_in[11], d_in[14], d_in[17], d_in[20]};
    const void* sw[4] = {d_in[12], d_in[15], d_in[18], d_in[21]};

    // ---- workspace layout (bytes), every region 256B-aligned ----
    char* base = (char*)d_ws;
    size_t off = 0;
    auto alloc = [&](size_t bytes) { char* p = base + off; off += (bytes + 255) & ~(size_t)255; return p; };
    int*    flags   = (int*)alloc(64 * 4);
    int*    rowptr  = (int*)alloc((size_t)(NN + 1) * 4);
    int*    cursor  = (int*)alloc((size_t)NN * 4);
    int*    csr_src = (int*)alloc((size_t)NE * 4);
    int*    partials= (int*)alloc((size_t)SCAN_NBLK * 4);
    float*  weakP   = (float*)alloc((size_t)NN * 4 * 4);
    float*  B3      = (float*)alloc((size_t)NN * 4 * 4);
    float*  C3      = (float*)alloc((size_t)NN * 4 * 4);
    __half* e2T     = (__half*)alloc((size_t)256 * 256 * 2);
    __half* wcatT   = (__half*)alloc((size_t)3 * 256 * 512 * 2);
    __half* W8T     = (__half*)alloc((size_t)16 * 256 * 2);
    __half* buf0    = (__half*)alloc((size_t)NN * HID * 2);
    __half* buf1    = (__half*)alloc((size_t)NN * HID * 2);
    // total ≈ 220.4 MB (proven working budget)

    if (ws_size && off > ws_size) {
        hipMemsetAsync(d_out, 0, (size_t)out_size * 2, stream);
        return;
    }

    const int gGemm = 782;                     // ceil(200000/256), 1024-thread blocks
    const int gGath = 25000;                   // 200000 / 8 rows per block
    const int gEdge = (NE + 255) / 256;        // 3125
    const int gNode1 = (NN + 255) / 256;       // 782

    detect_kernel<<<1, 64, 0, stream>>>(x, ei, flags);

    // weight prep (transposed f16)
    prepT256_kernel<<<256, 256, 0, stream>>>(e2, flags, e2T);
    prepT512_kernel<<<512, 256, 0, stream>>>(rw[0], sw[0], flags, wcatT);
    prepT512_kernel<<<512, 256, 0, stream>>>(rw[1], sw[1], flags, wcatT + (size_t)256 * 512);
    prepT512_kernel<<<512, 256, 0, stream>>>(rw[2], sw[2], flags, wcatT + (size_t)2 * 256 * 512);
    prepW8_kernel<<<16, 256, 0, stream>>>(rw[3], sw[3], flags, W8T);

    // CSR build
    zeroI_kernel<<<(NN + 1 + 255) / 256, 256, 0, stream>>>(rowptr, NN + 1);
    zeroI_kernel<<<gNode1, 256, 0, stream>>>(cursor, NN);
    count_kernel<<<gEdge, 256, 0, stream>>>(ei, flags, rowptr);
    scanA_kernel<<<SCAN_NBLK, 256, 0, stream>>>(rowptr, partials);
    scanB_kernel<<<1, 256, 0, stream>>>(partials);
    scanC_kernel<<<SCAN_NBLK, 256, 0, stream>>>(rowptr, partials);
    fill_kernel<<<gEdge, 256, 0, stream>>>(ei, flags, rowptr, cursor, csr_src);

    // front: T -> buf0 (f16), weak -> weakP (f32)
    frontT_kernel<<<2048, 256, 0, stream>>>(x, e1, be1, flags, buf0);
    frontW_kernel<<<2048, 256, 0, stream>>>(x, w1, b1, w2, b2, flags, weakP);

    // h0 = T @ e2 + be2 -> buf1
    mfma_gemm_kernel<256, 0><<<gGemm, 1024, 0, stream>>>(buf0, nullptr, e2T, be2, flags, buf1);

    // conv0: AGG(buf0) = gather(h0=buf1); buf0 = relu([AGG|h0] @ [rw0;sw0] + rb0)
    gather_kernel<<<gGath, 256, 0, stream>>>(rowptr, csr_src, buf1, buf0);
    mfma_gemm_kernel<512, 1><<<gGemm, 1024, 0, stream>>>(buf0, buf1, wcatT, rb[0], flags, buf0);

    // conv1
    gather_kernel<<<gGath, 256, 0, stream>>>(rowptr, csr_src, buf0, buf1);
    mfma_gemm_kernel<512, 1><<<gGemm, 1024, 0, stream>>>(buf1, buf0, wcatT + (size_t)256 * 512, rb[1], flags, buf1);

    // conv2
    gather_kernel<<<gGath, 256, 0, stream>>>(rowptr, csr_src, buf1, buf0);
    mfma_gemm_kernel<512, 1><<<gGemm, 1024, 0, stream>>>(buf0, buf1, wcatT + (size_t)2 * 256 * 512, rb[2], flags, buf0);

    // conv3 (strong, width 4): [B3|C3] = h @ [rw3|sw3] (+rb3 on C3); C3 += gather(B3)
    gemv3_mfma_kernel<<<1563, 256, 0, stream>>>(buf0, W8T, rb[3], flags, B3, C3);
    gather3_kernel<<<gNode1, 256, 0, stream>>>(rowptr, csr_src, B3, C3);

    // gate
    final_kernel<<<gNode1, 256, 0, stream>>>(weakP, C3, flags, d_out);
}

// Round 15
// 715.012 us; speedup vs baseline: 1.0621x; 1.0621x over previous
//
#include <hip/hip_runtime.h>
#include <hip/hip_bf16.h>
#include <hip/hip_fp16.h>

#define NN 200000
#define NE 800000
#define HID 256
#define SCAN_NBLK 196     // 196 * 1024 = 200704 >= NN+1

typedef __attribute__((ext_vector_type(8))) _Float16 f16x8;
typedef __attribute__((ext_vector_type(4))) float    f32x4;

// ---------- direct global->LDS DMA (16B/lane; LDS dest = wave base + lane*16) ----------
__device__ __forceinline__ void gload16(const void* g, void* l) {
    __builtin_amdgcn_global_load_lds(
        (__attribute__((address_space(1))) void*)(g),
        (__attribute__((address_space(3))) void*)(l), 16, 0, 0);
}

// ---------- packed f16 helpers ----------
__device__ __forceinline__ float2 upk(unsigned int u) {
    __half2 h = __builtin_bit_cast(__half2, u);
    return make_float2(__low2float(h), __high2float(h));
}
__device__ __forceinline__ unsigned int pk(float a, float b) {
    __half2 h = __floats2half2_rn(a, b);
    return __builtin_bit_cast(unsigned int, h);
}

// ---------- input dtype helpers (runtime-dispatched via flags) ----------
__device__ __forceinline__ float bfu(unsigned short u) {
    return __uint_as_float(((unsigned int)u) << 16);
}
__device__ __forceinline__ unsigned short f2bf(float f) {
    unsigned int u = __float_as_uint(f);
    return (unsigned short)((u + 0x7FFFu + ((u >> 16) & 1u)) >> 16);
}
__device__ __forceinline__ float ldF(const void* p, size_t i, int bf) {
    return bf ? bfu(((const unsigned short*)p)[i]) : ((const float*)p)[i];
}
__device__ __forceinline__ float4 ld4(const void* p, size_t i, int bf) {
    if (bf) {
        ushort4 u = *reinterpret_cast<const ushort4*>((const unsigned short*)p + i);
        return make_float4(bfu(u.x), bfu(u.y), bfu(u.z), bfu(u.w));
    }
    return *reinterpret_cast<const float4*>((const float*)p + i);
}
__device__ __forceinline__ void ld8(const void* p, size_t i, int bf, float* v) {
    if (bf) {
        ushort4 u0 = *reinterpret_cast<const ushort4*>((const unsigned short*)p + i);
        ushort4 u1 = *reinterpret_cast<const ushort4*>((const unsigned short*)p + i + 4);
        v[0] = bfu(u0.x); v[1] = bfu(u0.y); v[2] = bfu(u0.z); v[3] = bfu(u0.w);
        v[4] = bfu(u1.x); v[5] = bfu(u1.y); v[6] = bfu(u1.z); v[7] = bfu(u1.w);
    } else {
        float4 a = *reinterpret_cast<const float4*>((const float*)p + i);
        float4 b = *reinterpret_cast<const float4*>((const float*)p + i + 4);
        v[0] = a.x; v[1] = a.y; v[2] = a.z; v[3] = a.w;
        v[4] = b.x; v[5] = b.y; v[6] = b.z; v[7] = b.w;
    }
}
__device__ __forceinline__ int ldE(const int* ei, size_t i, int i64) {
    return i64 ? ei[2 * i] : ei[i];
}

// ---------- detector: flags[0]=floats-are-bf16, flags[1]=edges-are-int64 ----------
__global__ void detect_kernel(const void* x, const int* ei, int* flags)
{
    if (threadIdx.x == 0 && blockIdx.x == 0) {
        const unsigned short* xu = (const unsigned short*)x;
        int good = 0;
        for (int k = 0; k < 128; ++k) {
            float a = fabsf(bfu(xu[2 * k]));
            if (a == 0.f || (a >= 9.3e-10f && a <= 64.f)) ++good;
        }
        flags[0] = (good >= 64) ? 1 : 0;
        int zeros = 0;
        for (int k = 0; k < 128; ++k)
            if (ei[2 * k + 1] == 0) ++zeros;
        flags[1] = (zeros >= 64) ? 1 : 0;
    }
}

// ---------- weight prep: WT[n][256] = f16(W[k][n]) ----------
__global__ __launch_bounds__(256) void prepT256_kernel(
    const void* __restrict__ W, const int* __restrict__ flags, __half* __restrict__ WT)
{
    const int bf = flags[0];
    int id = blockIdx.x * 256 + threadIdx.x;     // 65536 total
    int k = id & 255, n = id >> 8;
    WT[(size_t)n * 256 + k] = __float2half_rn(ldF(W, (size_t)k * 256 + n, bf));
}

// ---------- weight prep: WT[n][512]: k<256 -> Rw[k][n], k>=256 -> Sw[k-256][n] ----------
__global__ __launch_bounds__(256) void prepT512_kernel(
    const void* __restrict__ Rw, const void* __restrict__ Sw,
    const int* __restrict__ flags, __half* __restrict__ WT)
{
    const int bf = flags[0];
    int id = blockIdx.x * 256 + threadIdx.x;     // 131072 total
    int k = id & 511, n = id >> 9;
    const void* src = (k < 256) ? Rw : Sw;
    WT[(size_t)n * 512 + k] = __float2half_rn(ldF(src, (size_t)(k & 255) * 256 + n, bf));
}

// ---------- weight prep: W8T[16][256]: c<4 -> rw3[k][c], c<8 -> sw3[k][c-4], else 0 ----------
__global__ __launch_bounds__(256) void prepW8_kernel(
    const void* __restrict__ rw3, const void* __restrict__ sw3,
    const int* __restrict__ flags, __half* __restrict__ W8T)
{
    const int bf = flags[0];
    int id = blockIdx.x * 256 + threadIdx.x;     // 4096 total
    int c = id >> 8, k = id & 255;
    float v = 0.f;
    if (c < 4)      v = ldF(rw3, (size_t)k * 4 + c, bf);
    else if (c < 8) v = ldF(sw3, (size_t)k * 4 + (c - 4), bf);
    W8T[(size_t)c * 256 + k] = __float2half_rn(v);
}

// ---------- frontT: T = relu(xs@e1+be1) (f16), reg-resident weights ----------
__global__ __launch_bounds__(256) void frontT_kernel(
    const void* __restrict__ x,
    const void* __restrict__ e1, const void* __restrict__ be1,
    const int* __restrict__ flags, __half* __restrict__ T)
{
    const int bf = flags[0];
    const int t = threadIdx.x;
    const int wave = t >> 6, lane = t & 63;
    const int half = lane >> 5, l32 = lane & 31;
    const int j0 = l32 * 8;

    float ev[6][8], be[8];
    ld8(be1, j0, bf, be);
#pragma unroll
    for (int k = 0; k < 6; ++k) ld8(e1, (size_t)k * HID + j0, bf, ev[k]);

    const int slot = blockIdx.x * 4 + wave;
    const int nslots = gridDim.x * 4;
    for (int n = slot * 2 + half; n < NN; n += nslots * 2) {
        float xs[6];
#pragma unroll
        for (int k = 0; k < 6; ++k) xs[k] = ldF(x, (size_t)n * 10 + 4 + k, bf);
        float a[8];
#pragma unroll
        for (int jj = 0; jj < 8; ++jj) a[jj] = be[jj];
#pragma unroll
        for (int k = 0; k < 6; ++k)
#pragma unroll
            for (int jj = 0; jj < 8; ++jj)
                a[jj] = fmaf(xs[k], ev[k][jj], a[jj]);
        uint4 o;
        o.x = pk(fmaxf(a[0], 0.f), fmaxf(a[1], 0.f));
        o.y = pk(fmaxf(a[2], 0.f), fmaxf(a[3], 0.f));
        o.z = pk(fmaxf(a[4], 0.f), fmaxf(a[5], 0.f));
        o.w = pk(fmaxf(a[6], 0.f), fmaxf(a[7], 0.f));
        *reinterpret_cast<uint4*>(&T[(size_t)n * HID + j0]) = o;
    }
}

// ---------- frontW: weak = relu(xs@w1+b1)@w2 + b2 (f32), reg-resident weights ----------
__global__ __launch_bounds__(256) void frontW_kernel(
    const void* __restrict__ x,
    const void* __restrict__ w1, const void* __restrict__ b1,
    const void* __restrict__ w2, const void* __restrict__ b2,
    const int* __restrict__ flags, float* __restrict__ weakO)
{
    const int bf = flags[0];
    const int t = threadIdx.x;
    const int wave = t >> 6, lane = t & 63;
    const int half = lane >> 5, l32 = lane & 31;
    const int j0 = l32 * 8;

    float wv[6][8], bb[8], w2r[8][4];
    ld8(b1, j0, bf, bb);
#pragma unroll
    for (int k = 0; k < 6; ++k) ld8(w1, (size_t)k * HID + j0, bf, wv[k]);
#pragma unroll
    for (int jj = 0; jj < 8; ++jj) {
        float4 r = ld4(w2, (size_t)(j0 + jj) * 4, bf);
        w2r[jj][0] = r.x; w2r[jj][1] = r.y; w2r[jj][2] = r.z; w2r[jj][3] = r.w;
    }
    float b2v[4];
#pragma unroll
    for (int c = 0; c < 4; ++c) b2v[c] = ldF(b2, c, bf);

    const int slot = blockIdx.x * 4 + wave;
    const int nslots = gridDim.x * 4;
    for (int n = slot * 2 + half; n < NN; n += nslots * 2) {
        float xs[6];
#pragma unroll
        for (int k = 0; k < 6; ++k) xs[k] = ldF(x, (size_t)n * 10 + 4 + k, bf);
        float a[8];
#pragma unroll
        for (int jj = 0; jj < 8; ++jj) a[jj] = bb[jj];
#pragma unroll
        for (int k = 0; k < 6; ++k)
#pragma unroll
            for (int jj = 0; jj < 8; ++jj)
                a[jj] = fmaf(xs[k], wv[k][jj], a[jj]);
        float wa[4] = {0.f, 0.f, 0.f, 0.f};
#pragma unroll
        for (int jj = 0; jj < 8; ++jj) {
            float av = fmaxf(a[jj], 0.f);
#pragma unroll
            for (int c = 0; c < 4; ++c) wa[c] = fmaf(av, w2r[jj][c], wa[c]);
        }
#pragma unroll
        for (int off = 16; off >= 1; off >>= 1)
#pragma unroll
            for (int c = 0; c < 4; ++c) wa[c] += __shfl_xor(wa[c], off);
        if (l32 == 0) {
            float4 w = {wa[0] + b2v[0], wa[1] + b2v[1], wa[2] + b2v[2], wa[3] + b2v[3]};
            *reinterpret_cast<float4*>(&weakO[(size_t)n * 4]) = w;
        }
    }
}

// ---------- MFMA GEMM (round-13 proven config): OUT = (relu?)(Acat @ Wcat + bias) ----------
// Block tile: 128 rows x 256 cols, 512 threads = 8 waves in 2x4 grid.
// In-place safe: block reads only its own 128 rows, writes after K-loop.
// Staging via global_load_lds, pre-swizzled global chunk: c=(t&3)^((t>>3)&3).
template<int KTOT, int RELU>
__global__ __launch_bounds__(512) void mfma_gemm_kernel(
    const __half* A0, const __half* __restrict__ A1,
    const __half* __restrict__ WT, const void* __restrict__ bias,
    const int* __restrict__ flags, __half* OUT)
{
    const int bf = flags[0];
    __shared__ alignas(16) __half As[128 * 32];
    __shared__ alignas(16) __half Ws[256 * 32];

    const int t    = threadIdx.x;
    const int bm   = blockIdx.x * 128;
    const int lane = t & 63;
    const int w    = t >> 6;                 // 8 waves
    const int wr   = w >> 2, wc = w & 3;     // 2 x 4 wave grid
    const int lr   = lane & 15, lg = lane >> 4;

    // per-thread source coordinates for staging (constant across K-steps)
    const int arow = t >> 2;
    int agm = bm + arow; if (agm > NN - 1) agm = NN - 1;   // clamp: pad rows discarded
    const int ac = (t & 3) ^ ((t >> 3) & 3);

    f32x4 acc[4][4] = {};

    for (int k0 = 0; k0 < KTOT; k0 += 32) {
        __syncthreads();
        // A tile: 128 rows x 32 k, one 16B DMA per thread
        {
            const __half* src = (KTOT == 512 && k0 >= 256) ? A1 : A0;
            const int kk0 = k0 & 255;
            gload16(&src[(size_t)agm * HID + kk0 + ac * 8], &As[w * 512]);
        }
        // W tile: 256 n x 32 k, two 16B DMAs per thread
#pragma unroll
        for (int p = 0; p < 2; ++p) {
            int cid = p * 512 + t;
            int n = cid >> 2;
            int c = (cid & 3) ^ ((cid >> 3) & 3);
            gload16(&WT[(size_t)n * KTOT + k0 + c * 8], &Ws[(p * 8 + w) * 512]);
        }
        __syncthreads();

        f16x8 a[4], b[4];
#pragma unroll
        for (int i = 0; i < 4; ++i) {
            int row = wr * 64 + i * 16 + lr;
            int sc = lg ^ ((row >> 1) & 3);
            a[i] = *reinterpret_cast<const f16x8*>(&As[row * 32 + sc * 8]);
        }
#pragma unroll
        for (int j = 0; j < 4; ++j) {
            int n = wc * 64 + j * 16 + lr;
            int sc = lg ^ ((n >> 1) & 3);
            b[j] = *reinterpret_cast<const f16x8*>(&Ws[n * 32 + sc * 8]);
        }
#pragma unroll
        for (int i = 0; i < 4; ++i)
#pragma unroll
            for (int j = 0; j < 4; ++j)
                acc[i][j] = __builtin_amdgcn_mfma_f32_16x16x32_f16(a[i], b[j], acc[i][j], 0, 0, 0);
    }

    float bv[4];
#pragma unroll
    for (int j = 0; j < 4; ++j) bv[j] = ldF(bias, wc * 64 + j * 16 + lr, bf);
#pragma unroll
    for (int i = 0; i < 4; ++i) {
        int rowBase = bm + wr * 64 + i * 16 + lg * 4;
#pragma unroll
        for (int r = 0; r < 4; ++r) {
            int gr = rowBase + r;
            if (gr < NN) {
#pragma unroll
                for (int j = 0; j < 4; ++j) {
                    int col = wc * 64 + j * 16 + lr;
                    float v = acc[i][j][r] + bv[j];
                    if (RELU) v = fmaxf(v, 0.f);
                    OUT[(size_t)gr * HID + col] = __float2half_rn(v);
                }
            }
        }
    }
}

// ---------- CSR build ----------
__global__ __launch_bounds__(256) void zeroI_kernel(int* __restrict__ p, int n)
{
    int i = blockIdx.x * 256 + threadIdx.x;
    if (i < n) p[i] = 0;
}

__global__ __launch_bounds__(256) void count_kernel(
    const int* __restrict__ ei, const int* __restrict__ flags, int* __restrict__ rowptr)
{
    const int i64 = flags[1];
    int e = blockIdx.x * 256 + threadIdx.x;
    if (e >= NE) return;
    int tgt = ldE(ei, (size_t)NE + e, i64);
    if ((unsigned)tgt < NN) atomicAdd(&rowptr[tgt + 1], 1);
}

// ---------- multi-block inclusive scan over rowptr[0..NN] ----------
__global__ __launch_bounds__(256) void scanA_kernel(
    const int* __restrict__ rowptr, int* __restrict__ partials)
{
    __shared__ int red[256];
    const int b = blockIdx.x, t = threadIdx.x;
    int base = b * 1024 + t * 4;
    int s = 0;
#pragma unroll
    for (int k = 0; k < 4; ++k) {
        int i = base + k;
        if (i <= NN) s += rowptr[i];
    }
    red[t] = s;
    __syncthreads();
    for (int off = 128; off >= 1; off >>= 1) {
        if (t < off) red[t] += red[t + off];
        __syncthreads();
    }
    if (t == 0) partials[b] = red[0];
}

__global__ __launch_bounds__(256) void scanB_kernel(int* __restrict__ partials)
{
    __shared__ int ps[256];
    const int t = threadIdx.x;
    int v = (t < SCAN_NBLK) ? partials[t] : 0;
    ps[t] = v;
    __syncthreads();
    for (int off = 1; off < 256; off <<= 1) {
        int u = (t >= off) ? ps[t - off] : 0;
        __syncthreads();
        ps[t] += u;
        __syncthreads();
    }
    if (t < SCAN_NBLK) partials[t] = ps[t] - v;   // exclusive block offset
}

__global__ __launch_bounds__(256) void scanC_kernel(
    int* __restrict__ rowptr, const int* __restrict__ partials)
{
    __shared__ int ts[256];
    const int b = blockIdx.x, t = threadIdx.x;
    int base = b * 1024 + t * 4;
    int v[4];
    int s = 0;
#pragma unroll
    for (int k = 0; k < 4; ++k) {
        int i = base + k;
        v[k] = (i <= NN) ? rowptr[i] : 0;
        s += v[k];
    }
    ts[t] = s;
    __syncthreads();
    for (int off = 1; off < 256; off <<= 1) {
        int u = (t >= off) ? ts[t - off] : 0;
        __syncthreads();
        ts[t] += u;
        __syncthreads();
    }
    int run = ts[t] - s + partials[b];
#pragma unroll
    for (int k = 0; k < 4; ++k) {
        int i = base + k;
        run += v[k];
        if (i <= NN) rowptr[i] = run;
    }
}

__global__ __launch_bounds__(256) void fill_kernel(
    const int* __restrict__ ei, const int* __restrict__ flags,
    const int* __restrict__ rowptr, int* __restrict__ cursor, int* __restrict__ csr_src)
{
    const int i64 = flags[1];
    int e = blockIdx.x * 256 + threadIdx.x;
    if (e >= NE) return;
    int src = ldE(ei, (size_t)e, i64);
    int tgt = ldE(ei, (size_t)NE + e, i64);
    if ((unsigned)src >= NN || (unsigned)tgt >= NN) return;
    int pos = rowptr[tgt] + atomicAdd(&cursor[tgt], 1);
    csr_src[pos] = src;
}

// ---------- gather v3: AGG[n] = sum_{j in CSR(n)} H[src_j] ----------
// 2 rows per wave (32 lanes/row, uint4=16B/lane); 4-way edge unroll for MLP.
__global__ __launch_bounds__(256) void gather_kernel(
    const int* __restrict__ rowptr, const int* __restrict__ csr_src,
    const __half* __restrict__ H, __half* __restrict__ AGG)
{
    const int t = threadIdx.x;
    const int wave = t >> 6, lane = t & 63;
    const int half = lane >> 5, l32 = lane & 31;
    int n = blockIdx.x * 8 + wave * 2 + half;
    if (n >= NN) return;
    int beg = rowptr[n], end = rowptr[n + 1];
    float a[8] = {0.f, 0.f, 0.f, 0.f, 0.f, 0.f, 0.f, 0.f};
    const size_t col = (size_t)l32 * 8;
    int j = beg;
    for (; j + 4 <= end; j += 4) {
        int s0 = csr_src[j], s1 = csr_src[j + 1], s2 = csr_src[j + 2], s3 = csr_src[j + 3];
        uint4 q0 = *reinterpret_cast<const uint4*>(&H[(size_t)s0 * HID + col]);
        uint4 q1 = *reinterpret_cast<const uint4*>(&H[(size_t)s1 * HID + col]);
        uint4 q2 = *reinterpret_cast<const uint4*>(&H[(size_t)s2 * HID + col]);
        uint4 q3 = *reinterpret_cast<const uint4*>(&H[(size_t)s3 * HID + col]);
        float2 p;
        p = upk(q0.x); a[0] += p.x; a[1] += p.y;
        p = upk(q0.y); a[2] += p.x; a[3] += p.y;
        p = upk(q0.z); a[4] += p.x; a[5] += p.y;
        p = upk(q0.w); a[6] += p.x; a[7] += p.y;
        p = upk(q1.x); a[0] += p.x; a[1] += p.y;
        p = upk(q1.y); a[2] += p.x; a[3] += p.y;
        p = upk(q1.z); a[4] += p.x; a[5] += p.y;
        p = upk(q1.w); a[6] += p.x; a[7] += p.y;
        p = upk(q2.x); a[0] += p.x; a[1] += p.y;
        p = upk(q2.y); a[2] += p.x; a[3] += p.y;
        p = upk(q2.z); a[4] += p.x; a[5] += p.y;
        p = upk(q2.w); a[6] += p.x; a[7] += p.y;
        p = upk(q3.x); a[0] += p.x; a[1] += p.y;
        p = upk(q3.y); a[2] += p.x; a[3] += p.y;
        p = upk(q3.z); a[4] += p.x; a[5] += p.y;
        p = upk(q3.w); a[6] += p.x; a[7] += p.y;
    }
    for (; j < end; ++j) {
        int s0 = csr_src[j];
        uint4 q0 = *reinterpret_cast<const uint4*>(&H[(size_t)s0 * HID + col]);
        float2 p;
        p = upk(q0.x); a[0] += p.x; a[1] += p.y;
        p = upk(q0.y); a[2] += p.x; a[3] += p.y;
        p = upk(q0.z); a[4] += p.x; a[5] += p.y;
        p = upk(q0.w); a[6] += p.x; a[7] += p.y;
    }
    uint4 o;
    o.x = pk(a[0], a[1]);
    o.y = pk(a[2], a[3]);
    o.z = pk(a[4], a[5]);
    o.w = pk(a[6], a[7]);
    *reinterpret_cast<uint4*>(&AGG[(size_t)n * HID + col]) = o;
}

// ---------- layer-3 skinny MFMA GEMM: [B3|C3] = h @ W8T^T ----------
__global__ __launch_bounds__(256) void gemv3_mfma_kernel(
    const __half* __restrict__ h, const __half* __restrict__ W8T,
    const void* __restrict__ rb3, const int* __restrict__ flags,
    float* __restrict__ B3, float* __restrict__ C3)
{
    const int bf = flags[0];
    __shared__ alignas(16) __half As[128 * 32];

    const int t    = threadIdx.x;
    const int bm   = blockIdx.x * 128;
    const int lane = t & 63;
    const int w    = t >> 6;                 // 4 waves, 32 rows each
    const int lr   = lane & 15, lg = lane >> 4;

    f32x4 acc[2] = {};

    for (int k0 = 0; k0 < HID; k0 += 32) {
        __syncthreads();
#pragma unroll
        for (int p = 0; p < 2; ++p) {
            int cid = p * 256 + t;
            int row = cid >> 2, c = cid & 3;
            int gm = bm + row;
            uint4 v = make_uint4(0, 0, 0, 0);
            if (gm < NN)
                v = *reinterpret_cast<const uint4*>(&h[(size_t)gm * HID + k0 + c * 8]);
            int sc = c ^ ((row >> 1) & 3);
            *reinterpret_cast<uint4*>(&As[row * 32 + sc * 8]) = v;
        }
        __syncthreads();

        f16x8 b = *reinterpret_cast<const f16x8*>(&W8T[(size_t)lr * HID + k0 + lg * 8]);
#pragma unroll
        for (int i = 0; i < 2; ++i) {
            int row = w * 32 + i * 16 + lr;
            int sc = lg ^ ((row >> 1) & 3);
            f16x8 a = *reinterpret_cast<const f16x8*>(&As[row * 32 + sc * 8]);
            acc[i] = __builtin_amdgcn_mfma_f32_16x16x32_f16(a, b, acc[i], 0, 0, 0);
        }
    }

    float rbv = (lr >= 4 && lr < 8) ? ldF(rb3, lr - 4, bf) : 0.f;
#pragma unroll
    for (int i = 0; i < 2; ++i) {
        int rowBase = bm + w * 32 + i * 16 + lg * 4;
#pragma unroll
        for (int r = 0; r < 4; ++r) {
            int gr = rowBase + r;
            if (gr < NN) {
                float v = acc[i][r];
                if (lr < 4)      B3[(size_t)gr * 4 + lr] = v;
                else if (lr < 8) C3[(size_t)gr * 4 + (lr - 4)] = v + rbv;
            }
        }
    }
}

// ---------- gather width-4: C3[n] += sum B3[src] ----------
__global__ __launch_bounds__(256) void gather3_kernel(
    const int* __restrict__ rowptr, const int* __restrict__ csr_src,
    const float* __restrict__ B3, float* __restrict__ C3)
{
    int n = blockIdx.x * 256 + threadIdx.x;
    if (n >= NN) return;
    int beg = rowptr[n], end = rowptr[n + 1];
    float4 acc = *reinterpret_cast<const float4*>(&C3[(size_t)n * 4]);
    for (int j = beg; j < end; ++j) {
        int s = csr_src[j];
        float4 v = *reinterpret_cast<const float4*>(&B3[(size_t)s * 4]);
        acc.x += v.x; acc.y += v.y; acc.z += v.z; acc.w += v.w;
    }
    *reinterpret_cast<float4*>(&C3[(size_t)n * 4]) = acc;
}

// ---------- final: confidence gating; dtype-dispatched output ----------
__global__ __launch_bounds__(256) void final_kernel(
    const float* __restrict__ weakO, const float* __restrict__ strongO,
    const int* __restrict__ flags, void* __restrict__ outv)
{
    const int bf = flags[0];
    int n = blockIdx.x * 256 + threadIdx.x;
    if (n >= NN) return;
    float4 w = *reinterpret_cast<const float4*>(&weakO[(size_t)n * 4]);
    float4 s = *reinterpret_cast<const float4*>(&strongO[(size_t)n * 4]);
    float mx = fmaxf(fmaxf(w.x, w.y), fmaxf(w.z, w.w));
    float e0 = expf(w.x - mx), e1 = expf(w.y - mx), e2 = expf(w.z - mx), e3 = expf(w.w - mx);
    float inv = 1.f / (e0 + e1 + e2 + e3);
    float p0 = e0 * inv, p1 = e1 * inv, p2 = e2 * inv, p3 = e3 * inv;
    const float m = 0.25f;
    float var = ((p0 - m) * (p0 - m) + (p1 - m) * (p1 - m) +
                 (p2 - m) * (p2 - m) + (p3 - m) * (p3 - m)) * 0.25f;
    float ent = -(p0 * logf(p0 + 1e-8f) + p1 * logf(p1 + 1e-8f) +
                  p2 * logf(p2 + 1e-8f) + p3 * logf(p3 + 1e-8f));
    ent *= 0.7213475204444817f;  // 1/log(4)
    float conf = 0.5f * (var + (1.f - ent));
    conf = fminf(fmaxf(conf, 0.f), 1.f);
    float o0 = conf * w.x + (1.f - conf) * s.x;
    float o1 = conf * w.y + (1.f - conf) * s.y;
    float o2 = conf * w.z + (1.f - conf) * s.z;
    float o3 = conf * w.w + (1.f - conf) * s.w;
    if (bf) {
        ushort4 u;
        u.x = f2bf(o0); u.y = f2bf(o1); u.z = f2bf(o2); u.w = f2bf(o3);
        *reinterpret_cast<ushort4*>((unsigned short*)outv + (size_t)n * 4) = u;
    } else {
        float4 o = {o0, o1, o2, o3};
        *reinterpret_cast<float4*>((float*)outv + (size_t)n * 4) = o;
    }
}

extern "C" void kernel_launch(void* const* d_in, const int* in_sizes, int n_in,
                              void* d_out, int out_size, void* d_ws, size_t ws_size,
                              hipStream_t stream)
{
    const void* x   = d_in[0];
    const int*  ei  = (const int*)d_in[1];
    const void* w1  = d_in[2];
    const void* b1  = d_in[3];
    const void* w2  = d_in[4];
    const void* b2  = d_in[5];
    const void* e1  = d_in[6];
    const void* be1 = d_in[7];
    const void* e2  = d_in[8];
    const void* be2 = d_in[9];
    const void* rw[4] = {d_in[10], d_in[13], d_in[16], d_in[19]};
    const void* rb[4] = {d_in[11], d_in[14], d_in[17], d_in[20]};
    const void* sw[4] = {d_in[12], d_in[15], d_in[18], d_in[21]};

    // ---- workspace layout (bytes), every region 256B-aligned ----
    char* base = (char*)d_ws;
    size_t off = 0;
    auto alloc = [&](size_t bytes) { char* p = base + off; off += (bytes + 255) & ~(size_t)255; return p; };
    int*    flags   = (int*)alloc(64 * 4);
    int*    rowptr  = (int*)alloc((size_t)(NN + 1) * 4);
    int*    cursor  = (int*)alloc((size_t)NN * 4);
    int*    csr_src = (int*)alloc((size_t)NE * 4);
    int*    partials= (int*)alloc((size_t)SCAN_NBLK * 4);
    float*  weakP   = (float*)alloc((size_t)NN * 4 * 4);
    float*  B3      = (float*)alloc((size_t)NN * 4 * 4);
    float*  C3      = (float*)alloc((size_t)NN * 4 * 4);
    __half* e2T     = (__half*)alloc((size_t)256 * 256 * 2);
    __half* wcatT   = (__half*)alloc((size_t)3 * 256 * 512 * 2);
    __half* W8T     = (__half*)alloc((size_t)16 * 256 * 2);
    __half* buf0    = (__half*)alloc((size_t)NN * HID * 2);
    __half* buf1    = (__half*)alloc((size_t)NN * HID * 2);
    // total ≈ 220.4 MB (proven working budget)

    if (ws_size && off > ws_size) {
        hipMemsetAsync(d_out, 0, (size_t)out_size * 2, stream);
        return;
    }

    const int gGemm = 1563;                    // ceil(200000/128), 512-thread blocks
    const int gGath = 25000;                   // 200000 / 8 rows per block
    const int gEdge = (NE + 255) / 256;        // 3125
    const int gNode1 = (NN + 255) / 256;       // 782

    detect_kernel<<<1, 64, 0, stream>>>(x, ei, flags);

    // weight prep (transposed f16)
    prepT256_kernel<<<256, 256, 0, stream>>>(e2, flags, e2T);
    prepT512_kernel<<<512, 256, 0, stream>>>(rw[0], sw[0], flags, wcatT);
    prepT512_kernel<<<512, 256, 0, stream>>>(rw[1], sw[1], flags, wcatT + (size_t)256 * 512);
    prepT512_kernel<<<512, 256, 0, stream>>>(rw[2], sw[2], flags, wcatT + (size_t)2 * 256 * 512);
    prepW8_kernel<<<16, 256, 0, stream>>>(rw[3], sw[3], flags, W8T);

    // CSR build
    zeroI_kernel<<<(NN + 1 + 255) / 256, 256, 0, stream>>>(rowptr, NN + 1);
    zeroI_kernel<<<gNode1, 256, 0, stream>>>(cursor, NN);
    count_kernel<<<gEdge, 256, 0, stream>>>(ei, flags, rowptr);
    scanA_kernel<<<SCAN_NBLK, 256, 0, stream>>>(rowptr, partials);
    scanB_kernel<<<1, 256, 0, stream>>>(partials);
    scanC_kernel<<<SCAN_NBLK, 256, 0, stream>>>(rowptr, partials);
    fill_kernel<<<gEdge, 256, 0, stream>>>(ei, flags, rowptr, cursor, csr_src);

    // front: T -> buf0 (f16), weak -> weakP (f32)
    frontT_kernel<<<2048, 256, 0, stream>>>(x, e1, be1, flags, buf0);
    frontW_kernel<<<2048, 256, 0, stream>>>(x, w1, b1, w2, b2, flags, weakP);

    // h0 = T @ e2 + be2 -> buf1
    mfma_gemm_kernel<256, 0><<<gGemm, 512, 0, stream>>>(buf0, nullptr, e2T, be2, flags, buf1);

    // conv0: AGG(buf0) = gather(h0=buf1); buf0 = relu([AGG|h0] @ [rw0;sw0] + rb0)
    gather_kernel<<<gGath, 256, 0, stream>>>(rowptr, csr_src, buf1, buf0);
    mfma_gemm_kernel<512, 1><<<gGemm, 512, 0, stream>>>(buf0, buf1, wcatT, rb[0], flags, buf0);

    // conv1
    gather_kernel<<<gGath, 256, 0, stream>>>(rowptr, csr_src, buf0, buf1);
    mfma_gemm_kernel<512, 1><<<gGemm, 512, 0, stream>>>(buf1, buf0, wcatT + (size_t)256 * 512, rb[1], flags, buf1);

    // conv2
    gather_kernel<<<gGath, 256, 0, stream>>>(rowptr, csr_src, buf1, buf0);
    mfma_gemm_kernel<512, 1><<<gGemm, 512, 0, stream>>>(buf0, buf1, wcatT + (size_t)2 * 256 * 512, rb[2], flags, buf0);

    // conv3 (strong, width 4): [B3|C3] = h @ [rw3|sw3] (+rb3 on C3); C3 += gather(B3)
    gemv3_mfma_kernel<<<gGemm, 256, 0, stream>>>(buf0, W8T, rb[3], flags, B3, C3);
    gather3_kernel<<<gNode1, 256, 0, stream>>>(rowptr, csr_src, B3, C3);

    // gate
    final_kernel<<<gNode1, 256, 0, stream>>>(weakP, C3, flags, d_out);
}

// Round 16
// 705.538 us; speedup vs baseline: 1.0764x; 1.0134x over previous
//
#include <hip/hip_runtime.h>
#include <hip/hip_bf16.h>
#include <hip/hip_fp16.h>

#define NN 200000
#define NE 800000
#define HID 256
#define SCAN_NBLK 196     // 196 * 1024 = 200704 >= NN+1

typedef __attribute__((ext_vector_type(8))) _Float16 f16x8;
typedef __attribute__((ext_vector_type(4))) float    f32x4;

// ---------- direct global->LDS DMA (16B/lane; LDS dest = wave base + lane*16) ----------
__device__ __forceinline__ void gload16(const void* g, void* l) {
    __builtin_amdgcn_global_load_lds(
        (__attribute__((address_space(1))) void*)(g),
        (__attribute__((address_space(3))) void*)(l), 16, 0, 0);
}

// ---------- packed f16 helpers ----------
__device__ __forceinline__ float2 upk(unsigned int u) {
    __half2 h = __builtin_bit_cast(__half2, u);
    return make_float2(__low2float(h), __high2float(h));
}
__device__ __forceinline__ unsigned int pk(float a, float b) {
    __half2 h = __floats2half2_rn(a, b);
    return __builtin_bit_cast(unsigned int, h);
}

// ---------- input dtype helpers (runtime-dispatched via flags) ----------
__device__ __forceinline__ float bfu(unsigned short u) {
    return __uint_as_float(((unsigned int)u) << 16);
}
__device__ __forceinline__ unsigned short f2bf(float f) {
    unsigned int u = __float_as_uint(f);
    return (unsigned short)((u + 0x7FFFu + ((u >> 16) & 1u)) >> 16);
}
__device__ __forceinline__ float ldF(const void* p, size_t i, int bf) {
    return bf ? bfu(((const unsigned short*)p)[i]) : ((const float*)p)[i];
}
__device__ __forceinline__ float4 ld4(const void* p, size_t i, int bf) {
    if (bf) {
        ushort4 u = *reinterpret_cast<const ushort4*>((const unsigned short*)p + i);
        return make_float4(bfu(u.x), bfu(u.y), bfu(u.z), bfu(u.w));
    }
    return *reinterpret_cast<const float4*>((const float*)p + i);
}
__device__ __forceinline__ void ld8(const void* p, size_t i, int bf, float* v) {
    if (bf) {
        ushort4 u0 = *reinterpret_cast<const ushort4*>((const unsigned short*)p + i);
        ushort4 u1 = *reinterpret_cast<const ushort4*>((const unsigned short*)p + i + 4);
        v[0] = bfu(u0.x); v[1] = bfu(u0.y); v[2] = bfu(u0.z); v[3] = bfu(u0.w);
        v[4] = bfu(u1.x); v[5] = bfu(u1.y); v[6] = bfu(u1.z); v[7] = bfu(u1.w);
    } else {
        float4 a = *reinterpret_cast<const float4*>((const float*)p + i);
        float4 b = *reinterpret_cast<const float4*>((const float*)p + i + 4);
        v[0] = a.x; v[1] = a.y; v[2] = a.z; v[3] = a.w;
        v[4] = b.x; v[5] = b.y; v[6] = b.z; v[7] = b.w;
    }
}
__device__ __forceinline__ int ldE(const int* ei, size_t i, int i64) {
    return i64 ? ei[2 * i] : ei[i];
}

// ---------- detector: flags[0]=floats-are-bf16, flags[1]=edges-are-int64 ----------
__global__ void detect_kernel(const void* x, const int* ei, int* flags)
{
    if (threadIdx.x == 0 && blockIdx.x == 0) {
        const unsigned short* xu = (const unsigned short*)x;
        int good = 0;
        for (int k = 0; k < 128; ++k) {
            float a = fabsf(bfu(xu[2 * k]));
            if (a == 0.f || (a >= 9.3e-10f && a <= 64.f)) ++good;
        }
        flags[0] = (good >= 64) ? 1 : 0;
        int zeros = 0;
        for (int k = 0; k < 128; ++k)
            if (ei[2 * k + 1] == 0) ++zeros;
        flags[1] = (zeros >= 64) ? 1 : 0;
    }
}

// ---------- weight prep: WT[n][256] = f16(W[k][n]) ----------
__global__ __launch_bounds__(256) void prepT256_kernel(
    const void* __restrict__ W, const int* __restrict__ flags, __half* __restrict__ WT)
{
    const int bf = flags[0];
    int id = blockIdx.x * 256 + threadIdx.x;     // 65536 total
    int k = id & 255, n = id >> 8;
    WT[(size_t)n * 256 + k] = __float2half_rn(ldF(W, (size_t)k * 256 + n, bf));
}

// ---------- weight prep: WT[n][512]: k<256 -> Rw[k][n], k>=256 -> Sw[k-256][n] ----------
__global__ __launch_bounds__(256) void prepT512_kernel(
    const void* __restrict__ Rw, const void* __restrict__ Sw,
    const int* __restrict__ flags, __half* __restrict__ WT)
{
    const int bf = flags[0];
    int id = blockIdx.x * 256 + threadIdx.x;     // 131072 total
    int k = id & 511, n = id >> 9;
    const void* src = (k < 256) ? Rw : Sw;
    WT[(size_t)n * 512 + k] = __float2half_rn(ldF(src, (size_t)(k & 255) * 256 + n, bf));
}

// ---------- weight prep: W8T[16][256]: c<4 -> rw3[k][c], c<8 -> sw3[k][c-4], else 0 ----------
__global__ __launch_bounds__(256) void prepW8_kernel(
    const void* __restrict__ rw3, const void* __restrict__ sw3,
    const int* __restrict__ flags, __half* __restrict__ W8T)
{
    const int bf = flags[0];
    int id = blockIdx.x * 256 + threadIdx.x;     // 4096 total
    int c = id >> 8, k = id & 255;
    float v = 0.f;
    if (c < 4)      v = ldF(rw3, (size_t)k * 4 + c, bf);
    else if (c < 8) v = ldF(sw3, (size_t)k * 4 + (c - 4), bf);
    W8T[(size_t)c * 256 + k] = __float2half_rn(v);
}

// ---------- frontT: T = relu(xs@e1+be1) (f16), reg-resident weights ----------
__global__ __launch_bounds__(256) void frontT_kernel(
    const void* __restrict__ x,
    const void* __restrict__ e1, const void* __restrict__ be1,
    const int* __restrict__ flags, __half* __restrict__ T)
{
    const int bf = flags[0];
    const int t = threadIdx.x;
    const int wave = t >> 6, lane = t & 63;
    const int half = lane >> 5, l32 = lane & 31;
    const int j0 = l32 * 8;

    float ev[6][8], be[8];
    ld8(be1, j0, bf, be);
#pragma unroll
    for (int k = 0; k < 6; ++k) ld8(e1, (size_t)k * HID + j0, bf, ev[k]);

    const int slot = blockIdx.x * 4 + wave;
    const int nslots = gridDim.x * 4;
    for (int n = slot * 2 + half; n < NN; n += nslots * 2) {
        float xs[6];
#pragma unroll
        for (int k = 0; k < 6; ++k) xs[k] = ldF(x, (size_t)n * 10 + 4 + k, bf);
        float a[8];
#pragma unroll
        for (int jj = 0; jj < 8; ++jj) a[jj] = be[jj];
#pragma unroll
        for (int k = 0; k < 6; ++k)
#pragma unroll
            for (int jj = 0; jj < 8; ++jj)
                a[jj] = fmaf(xs[k], ev[k][jj], a[jj]);
        uint4 o;
        o.x = pk(fmaxf(a[0], 0.f), fmaxf(a[1], 0.f));
        o.y = pk(fmaxf(a[2], 0.f), fmaxf(a[3], 0.f));
        o.z = pk(fmaxf(a[4], 0.f), fmaxf(a[5], 0.f));
        o.w = pk(fmaxf(a[6], 0.f), fmaxf(a[7], 0.f));
        *reinterpret_cast<uint4*>(&T[(size_t)n * HID + j0]) = o;
    }
}

// ---------- frontW: weak = relu(xs@w1+b1)@w2 + b2 (f32), reg-resident weights ----------
__global__ __launch_bounds__(256) void frontW_kernel(
    const void* __restrict__ x,
    const void* __restrict__ w1, const void* __restrict__ b1,
    const void* __restrict__ w2, const void* __restrict__ b2,
    const int* __restrict__ flags, float* __restrict__ weakO)
{
    const int bf = flags[0];
    const int t = threadIdx.x;
    const int wave = t >> 6, lane = t & 63;
    const int half = lane >> 5, l32 = lane & 31;
    const int j0 = l32 * 8;

    float wv[6][8], bb[8], w2r[8][4];
    ld8(b1, j0, bf, bb);
#pragma unroll
    for (int k = 0; k < 6; ++k) ld8(w1, (size_t)k * HID + j0, bf, wv[k]);
#pragma unroll
    for (int jj = 0; jj < 8; ++jj) {
        float4 r = ld4(w2, (size_t)(j0 + jj) * 4, bf);
        w2r[jj][0] = r.x; w2r[jj][1] = r.y; w2r[jj][2] = r.z; w2r[jj][3] = r.w;
    }
    float b2v[4];
#pragma unroll
    for (int c = 0; c < 4; ++c) b2v[c] = ldF(b2, c, bf);

    const int slot = blockIdx.x * 4 + wave;
    const int nslots = gridDim.x * 4;
    for (int n = slot * 2 + half; n < NN; n += nslots * 2) {
        float xs[6];
#pragma unroll
        for (int k = 0; k < 6; ++k) xs[k] = ldF(x, (size_t)n * 10 + 4 + k, bf);
        float a[8];
#pragma unroll
        for (int jj = 0; jj < 8; ++jj) a[jj] = bb[jj];
#pragma unroll
        for (int k = 0; k < 6; ++k)
#pragma unroll
            for (int jj = 0; jj < 8; ++jj)
                a[jj] = fmaf(xs[k], wv[k][jj], a[jj]);
        float wa[4] = {0.f, 0.f, 0.f, 0.f};
#pragma unroll
        for (int jj = 0; jj < 8; ++jj) {
            float av = fmaxf(a[jj], 0.f);
#pragma unroll
            for (int c = 0; c < 4; ++c) wa[c] = fmaf(av, w2r[jj][c], wa[c]);
        }
#pragma unroll
        for (int off = 16; off >= 1; off >>= 1)
#pragma unroll
            for (int c = 0; c < 4; ++c) wa[c] += __shfl_xor(wa[c], off);
        if (l32 == 0) {
            float4 w = {wa[0] + b2v[0], wa[1] + b2v[1], wa[2] + b2v[2], wa[3] + b2v[3]};
            *reinterpret_cast<float4*>(&weakO[(size_t)n * 4]) = w;
        }
    }
}

// ---------- MFMA GEMM, 2-phase double-buffered (T3 minimum recipe) ----------
// Block tile: 128 rows x 256 cols, 512 threads = 8 waves in 2x4 grid.
// Per K-step: issue next tile's global_load_lds into buf^1, compute current
// buf, ONE __syncthreads() (implicit vmcnt/lgkm drain makes swap safe).
// In-place safe: block reads only its own 128 rows, writes after K-loop.
template<int KTOT, int RELU>
__global__ __launch_bounds__(512) void mfma_gemm_kernel(
    const __half* A0, const __half* __restrict__ A1,
    const __half* __restrict__ WT, const void* __restrict__ bias,
    const int* __restrict__ flags, __half* OUT)
{
    const int bf = flags[0];
    __shared__ alignas(16) __half As[2][128 * 32];
    __shared__ alignas(16) __half Ws[2][256 * 32];

    const int t    = threadIdx.x;
    const int bm   = blockIdx.x * 128;
    const int lane = t & 63;
    const int w    = t >> 6;                 // 8 waves
    const int wr   = w >> 2, wc = w & 3;     // 2 x 4 wave grid
    const int lr   = lane & 15, lg = lane >> 4;

    // per-thread staging coords (constant across K-steps)
    const int arow = t >> 2;
    int agm = bm + arow; if (agm > NN - 1) agm = NN - 1;   // clamp: pad rows discarded
    const int ac = (t & 3) ^ ((t >> 3) & 3);

    const int NS = KTOT / 32;

    auto stage = [&](int s, int b) {
        const int k0 = s * 32;
        const __half* srcA = (KTOT == 512 && k0 >= 256) ? A1 : A0;
        const int kk0 = k0 & 255;
        gload16(&srcA[(size_t)agm * HID + kk0 + ac * 8], &As[b][w * 512]);
#pragma unroll
        for (int p = 0; p < 2; ++p) {
            int cid = p * 512 + t;
            int n = cid >> 2;
            int c = (cid & 3) ^ ((cid >> 3) & 3);
            gload16(&WT[(size_t)n * KTOT + k0 + c * 8], &Ws[b][(p * 8 + w) * 512]);
        }
    };

    f32x4 acc[4][4] = {};

    stage(0, 0);
    __syncthreads();               // drain prologue DMAs

    int cur = 0;
    for (int s = 0; s < NS; ++s) {
        if (s + 1 < NS) stage(s + 1, cur ^ 1);   // async prefetch next tile

        f16x8 a[4], b[4];
#pragma unroll
        for (int i = 0; i < 4; ++i) {
            int row = wr * 64 + i * 16 + lr;
            int sc = lg ^ ((row >> 1) & 3);
            a[i] = *reinterpret_cast<const f16x8*>(&As[cur][row * 32 + sc * 8]);
        }
#pragma unroll
        for (int j = 0; j < 4; ++j) {
            int n = wc * 64 + j * 16 + lr;
            int sc = lg ^ ((n >> 1) & 3);
            b[j] = *reinterpret_cast<const f16x8*>(&Ws[cur][n * 32 + sc * 8]);
        }
#pragma unroll
        for (int i = 0; i < 4; ++i)
#pragma unroll
            for (int j = 0; j < 4; ++j)
                acc[i][j] = __builtin_amdgcn_mfma_f32_16x16x32_f16(a[i], b[j], acc[i][j], 0, 0, 0);

        __syncthreads();           // next-tile DMAs landed; current buf free
        cur ^= 1;
    }

    float bv[4];
#pragma unroll
    for (int j = 0; j < 4; ++j) bv[j] = ldF(bias, wc * 64 + j * 16 + lr, bf);
#pragma unroll
    for (int i = 0; i < 4; ++i) {
        int rowBase = bm + wr * 64 + i * 16 + lg * 4;
#pragma unroll
        for (int r = 0; r < 4; ++r) {
            int gr = rowBase + r;
            if (gr < NN) {
#pragma unroll
                for (int j = 0; j < 4; ++j) {
                    int col = wc * 64 + j * 16 + lr;
                    float v = acc[i][j][r] + bv[j];
                    if (RELU) v = fmaxf(v, 0.f);
                    OUT[(size_t)gr * HID + col] = __float2half_rn(v);
                }
            }
        }
    }
}

// ---------- CSR build ----------
__global__ __launch_bounds__(256) void zeroI_kernel(int* __restrict__ p, int n)
{
    int i = blockIdx.x * 256 + threadIdx.x;
    if (i < n) p[i] = 0;
}

__global__ __launch_bounds__(256) void count_kernel(
    const int* __restrict__ ei, const int* __restrict__ flags, int* __restrict__ rowptr)
{
    const int i64 = flags[1];
    int e = blockIdx.x * 256 + threadIdx.x;
    if (e >= NE) return;
    int tgt = ldE(ei, (size_t)NE + e, i64);
    if ((unsigned)tgt < NN) atomicAdd(&rowptr[tgt + 1], 1);
}

// ---------- multi-block inclusive scan over rowptr[0..NN] ----------
__global__ __launch_bounds__(256) void scanA_kernel(
    const int* __restrict__ rowptr, int* __restrict__ partials)
{
    __shared__ int red[256];
    const int b = blockIdx.x, t = threadIdx.x;
    int base = b * 1024 + t * 4;
    int s = 0;
#pragma unroll
    for (int k = 0; k < 4; ++k) {
        int i = base + k;
        if (i <= NN) s += rowptr[i];
    }
    red[t] = s;
    __syncthreads();
    for (int off = 128; off >= 1; off >>= 1) {
        if (t < off) red[t] += red[t + off];
        __syncthreads();
    }
    if (t == 0) partials[b] = red[0];
}

__global__ __launch_bounds__(256) void scanB_kernel(int* __restrict__ partials)
{
    __shared__ int ps[256];
    const int t = threadIdx.x;
    int v = (t < SCAN_NBLK) ? partials[t] : 0;
    ps[t] = v;
    __syncthreads();
    for (int off = 1; off < 256; off <<= 1) {
        int u = (t >= off) ? ps[t - off] : 0;
        __syncthreads();
        ps[t] += u;
        __syncthreads();
    }
    if (t < SCAN_NBLK) partials[t] = ps[t] - v;   // exclusive block offset
}

__global__ __launch_bounds__(256) void scanC_kernel(
    int* __restrict__ rowptr, const int* __restrict__ partials)
{
    __shared__ int ts[256];
    const int b = blockIdx.x, t = threadIdx.x;
    int base = b * 1024 + t * 4;
    int v[4];
    int s = 0;
#pragma unroll
    for (int k = 0; k < 4; ++k) {
        int i = base + k;
        v[k] = (i <= NN) ? rowptr[i] : 0;
        s += v[k];
    }
    ts[t] = s;
    __syncthreads();
    for (int off = 1; off < 256; off <<= 1) {
        int u = (t >= off) ? ts[t - off] : 0;
        __syncthreads();
        ts[t] += u;
        __syncthreads();
    }
    int run = ts[t] - s + partials[b];
#pragma unroll
    for (int k = 0; k < 4; ++k) {
        int i = base + k;
        run += v[k];
        if (i <= NN) rowptr[i] = run;
    }
}

__global__ __launch_bounds__(256) void fill_kernel(
    const int* __restrict__ ei, const int* __restrict__ flags,
    const int* __restrict__ rowptr, int* __restrict__ cursor, int* __restrict__ csr_src)
{
    const int i64 = flags[1];
    int e = blockIdx.x * 256 + threadIdx.x;
    if (e >= NE) return;
    int src = ldE(ei, (size_t)e, i64);
    int tgt = ldE(ei, (size_t)NE + e, i64);
    if ((unsigned)src >= NN || (unsigned)tgt >= NN) return;
    int pos = rowptr[tgt] + atomicAdd(&cursor[tgt], 1);
    csr_src[pos] = src;
}

// ---------- gather: AGG[n] = sum_{j in CSR(n)} H[src_j] ----------
// 2 rows per wave (32 lanes/row, uint4=16B/lane); 4-way edge unroll for MLP.
__global__ __launch_bounds__(256) void gather_kernel(
    const int* __restrict__ rowptr, const int* __restrict__ csr_src,
    const __half* __restrict__ H, __half* __restrict__ AGG)
{
    const int t = threadIdx.x;
    const int wave = t >> 6, lane = t & 63;
    const int half = lane >> 5, l32 = lane & 31;
    int n = blockIdx.x * 8 + wave * 2 + half;
    if (n >= NN) return;
    int beg = rowptr[n], end = rowptr[n + 1];
    float a[8] = {0.f, 0.f, 0.f, 0.f, 0.f, 0.f, 0.f, 0.f};
    const size_t col = (size_t)l32 * 8;
    int j = beg;
    for (; j + 4 <= end; j += 4) {
        int s0 = csr_src[j], s1 = csr_src[j + 1], s2 = csr_src[j + 2], s3 = csr_src[j + 3];
        uint4 q0 = *reinterpret_cast<const uint4*>(&H[(size_t)s0 * HID + col]);
        uint4 q1 = *reinterpret_cast<const uint4*>(&H[(size_t)s1 * HID + col]);
        uint4 q2 = *reinterpret_cast<const uint4*>(&H[(size_t)s2 * HID + col]);
        uint4 q3 = *reinterpret_cast<const uint4*>(&H[(size_t)s3 * HID + col]);
        float2 p;
        p = upk(q0.x); a[0] += p.x; a[1] += p.y;
        p = upk(q0.y); a[2] += p.x; a[3] += p.y;
        p = upk(q0.z); a[4] += p.x; a[5] += p.y;
        p = upk(q0.w); a[6] += p.x; a[7] += p.y;
        p = upk(q1.x); a[0] += p.x; a[1] += p.y;
        p = upk(q1.y); a[2] += p.x; a[3] += p.y;
        p = upk(q1.z); a[4] += p.x; a[5] += p.y;
        p = upk(q1.w); a[6] += p.x; a[7] += p.y;
        p = upk(q2.x); a[0] += p.x; a[1] += p.y;
        p = upk(q2.y); a[2] += p.x; a[3] += p.y;
        p = upk(q2.z); a[4] += p.x; a[5] += p.y;
        p = upk(q2.w); a[6] += p.x; a[7] += p.y;
        p = upk(q3.x); a[0] += p.x; a[1] += p.y;
        p = upk(q3.y); a[2] += p.x; a[3] += p.y;
        p = upk(q3.z); a[4] += p.x; a[5] += p.y;
        p = upk(q3.w); a[6] += p.x; a[7] += p.y;
    }
    for (; j < end; ++j) {
        int s0 = csr_src[j];
        uint4 q0 = *reinterpret_cast<const uint4*>(&H[(size_t)s0 * HID + col]);
        float2 p;
        p = upk(q0.x); a[0] += p.x; a[1] += p.y;
        p = upk(q0.y); a[2] += p.x; a[3] += p.y;
        p = upk(q0.z); a[4] += p.x; a[5] += p.y;
        p = upk(q0.w); a[6] += p.x; a[7] += p.y;
    }
    uint4 o;
    o.x = pk(a[0], a[1]);
    o.y = pk(a[2], a[3]);
    o.z = pk(a[4], a[5]);
    o.w = pk(a[6], a[7]);
    *reinterpret_cast<uint4*>(&AGG[(size_t)n * HID + col]) = o;
}

// ---------- layer-3 skinny MFMA GEMM: [B3|C3] = h @ W8T^T ----------
__global__ __launch_bounds__(256) void gemv3_mfma_kernel(
    const __half* __restrict__ h, const __half* __restrict__ W8T,
    const void* __restrict__ rb3, const int* __restrict__ flags,
    float* __restrict__ B3, float* __restrict__ C3)
{
    const int bf = flags[0];
    __shared__ alignas(16) __half As[128 * 32];

    const int t    = threadIdx.x;
    const int bm   = blockIdx.x * 128;
    const int lane = t & 63;
    const int w    = t >> 6;                 // 4 waves, 32 rows each
    const int lr   = lane & 15, lg = lane >> 4;

    f32x4 acc[2] = {};

    for (int k0 = 0; k0 < HID; k0 += 32) {
        __syncthreads();
#pragma unroll
        for (int p = 0; p < 2; ++p) {
            int cid = p * 256 + t;
            int row = cid >> 2, c = cid & 3;
            int gm = bm + row;
            uint4 v = make_uint4(0, 0, 0, 0);
            if (gm < NN)
                v = *reinterpret_cast<const uint4*>(&h[(size_t)gm * HID + k0 + c * 8]);
            int sc = c ^ ((row >> 1) & 3);
            *reinterpret_cast<uint4*>(&As[row * 32 + sc * 8]) = v;
        }
        __syncthreads();

        f16x8 b = *reinterpret_cast<const f16x8*>(&W8T[(size_t)lr * HID + k0 + lg * 8]);
#pragma unroll
        for (int i = 0; i < 2; ++i) {
            int row = w * 32 + i * 16 + lr;
            int sc = lg ^ ((row >> 1) & 3);
            f16x8 a = *reinterpret_cast<const f16x8*>(&As[row * 32 + sc * 8]);
            acc[i] = __builtin_amdgcn_mfma_f32_16x16x32_f16(a, b, acc[i], 0, 0, 0);
        }
    }

    float rbv = (lr >= 4 && lr < 8) ? ldF(rb3, lr - 4, bf) : 0.f;
#pragma unroll
    for (int i = 0; i < 2; ++i) {
        int rowBase = bm + w * 32 + i * 16 + lg * 4;
#pragma unroll
        for (int r = 0; r < 4; ++r) {
            int gr = rowBase + r;
            if (gr < NN) {
                float v = acc[i][r];
                if (lr < 4)      B3[(size_t)gr * 4 + lr] = v;
                else if (lr < 8) C3[(size_t)gr * 4 + (lr - 4)] = v + rbv;
            }
        }
    }
}

// ---------- gather width-4: C3[n] += sum B3[src] ----------
__global__ __launch_bounds__(256) void gather3_kernel(
    const int* __restrict__ rowptr, const int* __restrict__ csr_src,
    const float* __restrict__ B3, float* __restrict__ C3)
{
    int n = blockIdx.x * 256 + threadIdx.x;
    if (n >= NN) return;
    int beg = rowptr[n], end = rowptr[n + 1];
    float4 acc = *reinterpret_cast<const float4*>(&C3[(size_t)n * 4]);
    for (int j = beg; j < end; ++j) {
        int s = csr_src[j];
        float4 v = *reinterpret_cast<const float4*>(&B3[(size_t)s * 4]);
        acc.x += v.x; acc.y += v.y; acc.z += v.z; acc.w += v.w;
    }
    *reinterpret_cast<float4*>(&C3[(size_t)n * 4]) = acc;
}

// ---------- final: confidence gating; dtype-dispatched output ----------
__global__ __launch_bounds__(256) void final_kernel(
    const float* __restrict__ weakO, const float* __restrict__ strongO,
    const int* __restrict__ flags, void* __restrict__ outv)
{
    const int bf = flags[0];
    int n = blockIdx.x * 256 + threadIdx.x;
    if (n >= NN) return;
    float4 w = *reinterpret_cast<const float4*>(&weakO[(size_t)n * 4]);
    float4 s = *reinterpret_cast<const float4*>(&strongO[(size_t)n * 4]);
    float mx = fmaxf(fmaxf(w.x, w.y), fmaxf(w.z, w.w));
    float e0 = expf(w.x - mx), e1 = expf(w.y - mx), e2 = expf(w.z - mx), e3 = expf(w.w - mx);
    float inv = 1.f / (e0 + e1 + e2 + e3);
    float p0 = e0 * inv, p1 = e1 * inv, p2 = e2 * inv, p3 = e3 * inv;
    const float m = 0.25f;
    float var = ((p0 - m) * (p0 - m) + (p1 - m) * (p1 - m) +
                 (p2 - m) * (p2 - m) + (p3 - m) * (p3 - m)) * 0.25f;
    float ent = -(p0 * logf(p0 + 1e-8f) + p1 * logf(p1 + 1e-8f) +
                  p2 * logf(p2 + 1e-8f) + p3 * logf(p3 + 1e-8f));
    ent *= 0.7213475204444817f;  // 1/log(4)
    float conf = 0.5f * (var + (1.f - ent));
    conf = fminf(fmaxf(conf, 0.f), 1.f);
    float o0 = conf * w.x + (1.f - conf) * s.x;
    float o1 = conf * w.y + (1.f - conf) * s.y;
    float o2 = conf * w.z + (1.f - conf) * s.z;
    float o3 = conf * w.w + (1.f - conf) * s.w;
    if (bf) {
        ushort4 u;
        u.x = f2bf(o0); u.y = f2bf(o1); u.z = f2bf(o2); u.w = f2bf(o3);
        *reinterpret_cast<ushort4*>((unsigned short*)outv + (size_t)n * 4) = u;
    } else {
        float4 o = {o0, o1, o2, o3};
        *reinterpret_cast<float4*>((float*)outv + (size_t)n * 4) = o;
    }
}

extern "C" void kernel_launch(void* const* d_in, const int* in_sizes, int n_in,
                              void* d_out, int out_size, void* d_ws, size_t ws_size,
                              hipStream_t stream)
{
    const void* x   = d_in[0];
    const int*  ei  = (const int*)d_in[1];
    const void* w1  = d_in[2];
    const void* b1  = d_in[3];
    const void* w2  = d_in[4];
    const void* b2  = d_in[5];
    const void* e1  = d_in[6];
    const void* be1 = d_in[7];
    const void* e2  = d_in[8];
    const void* be2 = d_in[9];
    const void* rw[4] = {d_in[10], d_in[13], d_in[16], d_in[19]};
    const void* rb[4] = {d_in[11], d_in[14], d_in[17], d_in[20]};
    const void* sw[4] = {d_in[12], d_in[15], d_in[18], d_in[21]};

    // ---- workspace layout (bytes), every region 256B-aligned ----
    char* base = (char*)d_ws;
    size_t off = 0;
    auto alloc = [&](size_t bytes) { char* p = base + off; off += (bytes + 255) & ~(size_t)255; return p; };
    int*    flags   = (int*)alloc(64 * 4);
    int*    rowptr  = (int*)alloc((size_t)(NN + 1) * 4);
    int*    cursor  = (int*)alloc((size_t)NN * 4);
    int*    csr_src = (int*)alloc((size_t)NE * 4);
    int*    partials= (int*)alloc((size_t)SCAN_NBLK * 4);
    float*  weakP   = (float*)alloc((size_t)NN * 4 * 4);
    float*  B3      = (float*)alloc((size_t)NN * 4 * 4);
    float*  C3      = (float*)alloc((size_t)NN * 4 * 4);
    __half* e2T     = (__half*)alloc((size_t)256 * 256 * 2);
    __half* wcatT   = (__half*)alloc((size_t)3 * 256 * 512 * 2);
    __half* W8T     = (__half*)alloc((size_t)16 * 256 * 2);
    __half* buf0    = (__half*)alloc((size_t)NN * HID * 2);
    __half* buf1    = (__half*)alloc((size_t)NN * HID * 2);
    // total ≈ 220.4 MB (proven working budget)

    if (ws_size && off > ws_size) {
        hipMemsetAsync(d_out, 0, (size_t)out_size * 2, stream);
        return;
    }

    const int gGemm = 1563;                    // ceil(200000/128), 512-thread blocks
    const int gGath = 25000;                   // 200000 / 8 rows per block
    const int gEdge = (NE + 255) / 256;        // 3125
    const int gNode1 = (NN + 255) / 256;       // 782

    detect_kernel<<<1, 64, 0, stream>>>(x, ei, flags);

    // weight prep (transposed f16)
    prepT256_kernel<<<256, 256, 0, stream>>>(e2, flags, e2T);
    prepT512_kernel<<<512, 256, 0, stream>>>(rw[0], sw[0], flags, wcatT);
    prepT512_kernel<<<512, 256, 0, stream>>>(rw[1], sw[1], flags, wcatT + (size_t)256 * 512);
    prepT512_kernel<<<512, 256, 0, stream>>>(rw[2], sw[2], flags, wcatT + (size_t)2 * 256 * 512);
    prepW8_kernel<<<16, 256, 0, stream>>>(rw[3], sw[3], flags, W8T);

    // CSR build
    zeroI_kernel<<<(NN + 1 + 255) / 256, 256, 0, stream>>>(rowptr, NN + 1);
    zeroI_kernel<<<gNode1, 256, 0, stream>>>(cursor, NN);
    count_kernel<<<gEdge, 256, 0, stream>>>(ei, flags, rowptr);
    scanA_kernel<<<SCAN_NBLK, 256, 0, stream>>>(rowptr, partials);
    scanB_kernel<<<1, 256, 0, stream>>>(partials);
    scanC_kernel<<<SCAN_NBLK, 256, 0, stream>>>(rowptr, partials);
    fill_kernel<<<gEdge, 256, 0, stream>>>(ei, flags, rowptr, cursor, csr_src);

    // front: T -> buf0 (f16), weak -> weakP (f32)
    frontT_kernel<<<2048, 256, 0, stream>>>(x, e1, be1, flags, buf0);
    frontW_kernel<<<2048, 256, 0, stream>>>(x, w1, b1, w2, b2, flags, weakP);

    // h0 = T @ e2 + be2 -> buf1
    mfma_gemm_kernel<256, 0><<<gGemm, 512, 0, stream>>>(buf0, nullptr, e2T, be2, flags, buf1);

    // conv0: AGG(buf0) = gather(h0=buf1); buf0 = relu([AGG|h0] @ [rw0;sw0] + rb0)
    gather_kernel<<<gGath, 256, 0, stream>>>(rowptr, csr_src, buf1, buf0);
    mfma_gemm_kernel<512, 1><<<gGemm, 512, 0, stream>>>(buf0, buf1, wcatT, rb[0], flags, buf0);

    // conv1
    gather_kernel<<<gGath, 256, 0, stream>>>(rowptr, csr_src, buf0, buf1);
    mfma_gemm_kernel<512, 1><<<gGemm, 512, 0, stream>>>(buf1, buf0, wcatT + (size_t)256 * 512, rb[1], flags, buf1);

    // conv2
    gather_kernel<<<gGath, 256, 0, stream>>>(rowptr, csr_src, buf1, buf0);
    mfma_gemm_kernel<512, 1><<<gGemm, 512, 0, stream>>>(buf0, buf1, wcatT + (size_t)2 * 256 * 512, rb[2], flags, buf0);

    // conv3 (strong, width 4): [B3|C3] = h @ [rw3|sw3] (+rb3 on C3); C3 += gather(B3)
    gemv3_mfma_kernel<<<gGemm, 256, 0, stream>>>(buf0, W8T, rb[3], flags, B3, C3);
    gather3_kernel<<<gNode1, 256, 0, stream>>>(rowptr, csr_src, B3, C3);

    // gate
    final_kernel<<<gNode1, 256, 0, stream>>>(weakP, C3, flags, d_out);
}